// Round 10
// baseline (1855.665 us; speedup 1.0000x reference)
//
#include <hip/hip_runtime.h>
#include <hip/hip_cooperative_groups.h>

namespace cg = cooperative_groups;

#define EPSV 1e-5f
#define NBUCKET 64

typedef __attribute__((ext_vector_type(8))) short short8;
typedef __attribute__((ext_vector_type(4))) float float4v;

__host__ __device__ static inline int cdiv(int a, int b) { return (a + b - 1) / b; }
__host__ __device__ static inline int imin(int a, int b) { return a < b ? a : b; }
__host__ __device__ static inline int imax(int a, int b) { return a > b ? a : b; }

__device__ inline unsigned short f2bf(float x) {
  unsigned u = __float_as_uint(x);
  return (unsigned short)((u + 0x7FFFu + ((u >> 16) & 1u)) >> 16);
}
__device__ inline float bf2f(unsigned short u) {
  return __uint_as_float(((unsigned)u) << 16);
}

struct PrepArgs {
  const float* w[10];
  unsigned short* wt[10];
  int ci[10];
  int co[10];
  int wcum[11];
  const float* feats;
  unsigned short* featsb;
  int nfeat4;
  float* stats;
};

// grid-stride: zero stats + feats fp32->bf16 + weights fp32->bf16 transposed [27][CO][CI]
__global__ __launch_bounds__(256) void prep_kernel(PrepArgs p, long total) {
  const int nstat4 = 10 * NBUCKET * 128 / 4;
  for (long tid0 = (long)blockIdx.x * 256 + threadIdx.x; tid0 < total;
       tid0 += (long)gridDim.x * 256) {
    long tid = tid0;
    if (tid < nstat4) {
      ((float4*)p.stats)[tid] = make_float4(0.f, 0.f, 0.f, 0.f);
      continue;
    }
    tid -= nstat4;
    if (tid < p.nfeat4) {
      float4 v = ((const float4*)p.feats)[tid];
      ushort4 r;
      r.x = f2bf(v.x); r.y = f2bf(v.y); r.z = f2bf(v.z); r.w = f2bf(v.w);
      ((ushort4*)p.featsb)[tid] = r;
      continue;
    }
    tid -= p.nfeat4;
    if (tid >= p.wcum[10]) continue;
    int i = 0;
    while (tid >= p.wcum[i + 1]) ++i;
    int e = (int)(tid - p.wcum[i]);
    int ci = p.ci[i], co = p.co[i];
    int k = e / (ci * co);
    int r = e - k * (ci * co);
    int o = r / ci;
    int c = r - o * ci;
    p.wt[i][((long)k * co + o) * ci + c] = f2bf(p.w[i][((long)k * ci + c) * co + o]);
  }
}

// ================= conv phase: R1-proven MFMA gather-GEMM body =================
// Grid-stride over 64-row tiles; CO tiled in 16-wide slices via an internal cot loop
// (cooperative launches are 1D). nbr staged per tile through LDS (coalesced int4);
// weight slice [27][RB][CIP] staged per cot. RB = min(CO,16); dead lanes read a
// clamped B row (mm) and never store.
template<int CI, int CO>
__device__ void conv_phase(int* nbrT, unsigned short* Bs,
    const unsigned short* __restrict__ f, const int* __restrict__ nbr,
    const unsigned short* __restrict__ wt, unsigned short* __restrict__ y,
    float* __restrict__ stats, int nout, int ntiles) {
  constexpr int NCHUNK = (CI == 8) ? 7 : (CI == 16) ? 14 : (CI == 32) ? 27 : 54;
  constexpr int CIP = (CI == 64) ? 64 : (CI == 32) ? 40 : (CI == 16) ? 24 : 12;
  constexpr int RB = (CO < 16) ? CO : 16;
  constexpr int NCOT = (CO + 15) / 16;

  const int tid = threadIdx.x;
  const int lane = tid & 63;
  const int wid = tid >> 6;
  const int m = lane & 15;
  const int mm = m & (RB - 1);
  const int quad = lane >> 4;

  auto tapof = [&](int c) -> int {
    if constexpr (CI == 8) return c * 4 + quad;
    else if constexpr (CI == 16) return c * 2 + (quad >> 1);
    else if constexpr (CI == 32) return c;
    else return c >> 1;
  };
  auto cioof = [&](int c) -> int {
    if constexpr (CI == 8) return 0;
    else if constexpr (CI == 16) return (quad & 1) * 8;
    else if constexpr (CI == 32) return quad * 8;
    else return ((c & 1) << 5) + quad * 8;
  };
  auto baddr = [&](int tap, int r, int cio) -> int {
    if constexpr (CI == 64) {
      int byt = (tap * 16 + r) * 128 + cio * 2;
      byt ^= (r & 7) << 4;  // XOR-swizzle 16B slot within the 128B row
      return byt >> 1;
    } else {
      return (tap * RB + r) * CIP + cio;
    }
  };

  for (int cot = 0; cot < NCOT; ++cot) {
    const int cbase = cot * 16;
    const int co = cbase + m;
    const bool cok = co < CO;
    __syncthreads();  // all reads of Bs/nbrT from previous cot complete
    // ---- cooperative weight-slice load into LDS ----
    {
      constexpr int NC8 = CI / 8;
      for (int t = tid; t < 27 * RB * NC8; t += 256) {
        int tap = t / (RB * NC8);
        int r = t - tap * (RB * NC8);
        int mo = r / NC8;
        int c8 = (r - mo * NC8) * 8;
        short8 v;
#pragma unroll
        for (int q = 0; q < 8; ++q) v[q] = 0;
        int c = cbase + mo;
        if (c < CO) v = *(const short8*)(wt + ((long)tap * CO + c) * CI + c8);
        *(short8*)&Bs[baddr(tap, mo, c8)] = v;
      }
    }
    // first __syncthreads inside the tile loop orders Bs fill before any read

    float sum = 0.f, sq = 0.f;
    for (int tile = blockIdx.x; tile < ntiles; tile += gridDim.x) {
      const int rowb0 = tile * 64;
      // ---- cooperative nbr stage: contiguous int4 loads ----
      {
        const long base = (long)rowb0 * 27;
        const long lim = (long)nout * 27;
        for (int j = tid; j < 432; j += 256) {
          long g = base + j * 4;
          int4 v;
          if (g + 4 <= lim) {
            v = *(const int4*)(nbr + g);
          } else {
            v.x = (g + 0 < lim) ? nbr[g + 0] : -1;
            v.y = (g + 1 < lim) ? nbr[g + 1] : -1;
            v.z = (g + 2 < lim) ? nbr[g + 2] : -1;
            v.w = (g + 3 < lim) ? nbr[g + 3] : -1;
          }
          *(int4*)&nbrT[j * 4] = v;
        }
      }
      __syncthreads();

      const int rowb = rowb0 + wid * 16;
      const int lrow = (wid * 16 + m) * 27;
      float4v acc = {0.f, 0.f, 0.f, 0.f};

      if constexpr (CI <= 16) {
        int idxs[NCHUNK];
#pragma unroll
        for (int c = 0; c < NCHUNK; ++c) {
          int tap = tapof(c);
          idxs[c] = (tap < 27) ? nbrT[lrow + tap] : -1;
        }
        short8 A[NCHUNK];
#pragma unroll
        for (int c = 0; c < NCHUNK; ++c) {
          short8 a;
#pragma unroll
          for (int q = 0; q < 8; ++q) a[q] = 0;
          if (idxs[c] >= 0) a = *(const short8*)(f + (long)idxs[c] * CI + cioof(c));
          A[c] = a;
        }
#pragma unroll
        for (int c = 0; c < NCHUNK; ++c) {
          int tap = tapof(c);
          int tapc = tap < 27 ? tap : 26;  // A=0 masks the clamped B
          short8 bf = *(const short8*)&Bs[baddr(tapc, mm, cioof(c))];
          acc = __builtin_amdgcn_mfma_f32_16x16x32_bf16(A[c], bf, acc, 0, 0, 0);
        }
      } else {
        constexpr int G = 9;
        constexpr int NG = NCHUNK / G;
        short8 A[2][G];
        auto load_group = [&](int g, int bi) {
#pragma unroll
          for (int j = 0; j < G; ++j) {
            const int c = g * G + j;
            const int tap = tapof(c);
            int idx = nbrT[lrow + tap];
            short8 a;
#pragma unroll
            for (int q = 0; q < 8; ++q) a[q] = 0;
            if (idx >= 0) a = *(const short8*)(f + (long)idx * CI + cioof(c));
            A[bi][j] = a;
          }
        };
        load_group(0, 0);
#pragma unroll
        for (int g = 0; g < NG; ++g) {
          const int cur = g & 1;
          if (g + 1 < NG) load_group(g + 1, cur ^ 1);
#pragma unroll
          for (int j = 0; j < G; ++j) {
            const int c = g * G + j;
            short8 bf = *(const short8*)&Bs[baddr(tapof(c), mm, cioof(c))];
            acc = __builtin_amdgcn_mfma_f32_16x16x32_bf16(A[cur][j], bf, acc, 0, 0, 0);
          }
        }
      }

#pragma unroll
      for (int r = 0; r < 4; ++r) {
        float v = acc[r];
        int orow = rowb + quad * 4 + r;
        if (cok && orow < nout) y[(long)orow * CO + co] = f2bf(v);
        sum += v;
        sq = fmaf(v, v, sq);
      }
      __syncthreads();  // nbrT reused next tile
    }

    // one atomic pair per wave per cot
    sum += __shfl_xor(sum, 16); sq += __shfl_xor(sq, 16);
    sum += __shfl_xor(sum, 32); sq += __shfl_xor(sq, 32);
    if (quad == 0 && cok) {
      float* st = stats + ((((unsigned)blockIdx.x * 4 + wid) & (NBUCKET - 1)) << 7);
      atomicAdd(&st[co], sum);
      atomicAdd(&st[64 + co], sq);
    }
  }
}

// ---- BN+ReLU (+bf16 skip) phase, grid-stride; sA/sC are LDS scratch (2*CO floats) ----
template<int CO>
__device__ void bn_phase(float* sA, float* sC,
    const unsigned short* __restrict__ y, const float* __restrict__ stats,
    const float* __restrict__ g, const float* __restrict__ b,
    const unsigned short* __restrict__ skip, unsigned short* __restrict__ out,
    int nout, float inv_n) {
  for (int o = threadIdx.x; o < CO; o += 256) {
    float su = 0.f, sq = 0.f;
#pragma unroll 8
    for (int bk = 0; bk < NBUCKET; ++bk) {
      su += stats[bk * 128 + o];
      sq += stats[bk * 128 + 64 + o];
    }
    float mu = su * inv_n;
    float var = sq * inv_n - mu * mu;
    float a = g[o] * rsqrtf(var + EPSV);
    sA[o] = a;
    sC[o] = fmaf(-mu, a, b[o]);
  }
  __syncthreads();
  long total4 = (long)nout * CO / 4;
  for (long i4 = (long)blockIdx.x * 256 + threadIdx.x; i4 < total4;
       i4 += (long)gridDim.x * 256) {
    int o = (int)((i4 * 4) % CO);
    ushort4 v = ((const ushort4*)y)[i4];
    float vv[4] = {bf2f(v.x), bf2f(v.y), bf2f(v.z), bf2f(v.w)};
    unsigned short rr[4];
#pragma unroll
    for (int j = 0; j < 4; ++j) {
      float x = fmaxf(fmaf(vv[j], sA[o + j], sC[o + j]), 0.f);
      if (skip) x += bf2f(skip[i4 * 4 + j]);
      rr[j] = f2bf(x);
    }
    ushort4 r;
    r.x = rr[0]; r.y = rr[1]; r.z = rr[2]; r.w = rr[3];
    ((ushort4*)out)[i4] = r;
  }
}

// ---- tail phase: x0 = c0f + relu(bn(y9)); out0 = x0 @ lin_w.T; swl/sbn LDS scratch ----
__device__ void tail_phase(float* swl, float* sbn,
    const unsigned short* __restrict__ c0f, const float* __restrict__ st9,
    const float* __restrict__ g9, const float* __restrict__ b9, float inv_n,
    const float* __restrict__ lin_w, const unsigned short* __restrict__ y9,
    float* __restrict__ out0, float* __restrict__ x0, int n0) {
  if (threadIdx.x < 64) swl[threadIdx.x] = lin_w[threadIdx.x];
  if (threadIdx.x < 8) {
    int o = threadIdx.x;
    float su = 0.f, sq = 0.f;
#pragma unroll 8
    for (int bk = 0; bk < NBUCKET; ++bk) {
      su += st9[bk * 128 + o];
      sq += st9[bk * 128 + 64 + o];
    }
    float mu = su * inv_n;
    float var = sq * inv_n - mu * mu;
    float a = g9[o] * rsqrtf(var + EPSV);
    sbn[o] = a;
    sbn[8 + o] = fmaf(-mu, a, b9[o]);
  }
  __syncthreads();
  for (int n = blockIdx.x * 256 + (int)threadIdx.x; n < n0; n += gridDim.x * 256) {
    const ushort4* pr = (const ushort4*)(y9 + (long)n * 8);
    ushort4 r0 = pr[0], r1 = pr[1];
    unsigned short rw[8] = {r0.x, r0.y, r0.z, r0.w, r1.x, r1.y, r1.z, r1.w};
    const ushort4* pc = (const ushort4*)(c0f + (long)n * 8);
    ushort4 c0 = pc[0], c1 = pc[1];
    unsigned short cs[8] = {c0.x, c0.y, c0.z, c0.w, c1.x, c1.y, c1.z, c1.w};
    float xv[8];
#pragma unroll
    for (int c = 0; c < 8; ++c)
      xv[c] = bf2f(cs[c]) + fmaxf(fmaf(bf2f(rw[c]), sbn[c], sbn[8 + c]), 0.f);
    *(float4*)(x0 + (long)n * 8) = make_float4(xv[0], xv[1], xv[2], xv[3]);
    *(float4*)(x0 + (long)n * 8 + 4) = make_float4(xv[4], xv[5], xv[6], xv[7]);
    float ov[8];
#pragma unroll
    for (int j = 0; j < 8; ++j) {
      float s = 0.f;
#pragma unroll
      for (int c = 0; c < 8; ++c) s = fmaf(xv[c], swl[j * 8 + c], s);
      ov[j] = s;
    }
    *(float4*)(out0 + (long)n * 8) = make_float4(ov[0], ov[1], ov[2], ov[3]);
    *(float4*)(out0 + (long)n * 8 + 4) = make_float4(ov[4], ov[5], ov[6], ov[7]);
  }
}

// ================= merged cooperative kernels (conv -> grid.sync -> bn/tail) ========
struct CBArgs {
  const unsigned short* f;
  const int* nbr;
  const unsigned short* wt;
  unsigned short* yraw;
  float* stats;
  const float* g;
  const float* b;
  const unsigned short* skip;
  unsigned short* out;
  int nout;
  int ntiles;
  float inv_n;
};

template<int CI, int CO>
__global__ __launch_bounds__(256, 2) void conv_bn_kernel(CBArgs a) {
  constexpr int CIP = (CI == 64) ? 64 : (CI == 32) ? 40 : (CI == 16) ? 24 : 12;
  constexpr int RB = (CO < 16) ? CO : 16;
  __shared__ int nbrT[64 * 27];
  __shared__ unsigned short Bs[27 * RB * CIP];
  conv_phase<CI, CO>(nbrT, Bs, a.f, a.nbr, a.wt, a.yraw, a.stats, a.nout, a.ntiles);
  __threadfence();
  cg::this_grid().sync();
  __threadfence();
  float* sA = (float*)nbrT;  // reuse LDS (2*CO floats << nbrT size)
  float* sC = sA + CO;
  bn_phase<CO>(sA, sC, a.yraw, a.stats, a.g, a.b, a.skip, a.out, a.nout, a.inv_n);
}

template<int CI, int CO>
__global__ __launch_bounds__(256, 2) void conv_only_kernel(CBArgs a) {
  constexpr int CIP = (CI == 64) ? 64 : (CI == 32) ? 40 : (CI == 16) ? 24 : 12;
  constexpr int RB = (CO < 16) ? CO : 16;
  __shared__ int nbrT[64 * 27];
  __shared__ unsigned short Bs[27 * RB * CIP];
  conv_phase<CI, CO>(nbrT, Bs, a.f, a.nbr, a.wt, a.yraw, a.stats, a.nout, a.ntiles);
}

struct CTArgs {
  const unsigned short* f;
  const int* nbr;
  const unsigned short* wt;
  unsigned short* yraw;
  float* st9;
  const unsigned short* c0f;
  const float* g9;
  const float* b9;
  const float* lin_w;
  float* out0;
  float* x0;
  int n0;
  int ntiles;
  float inv_n;
};

__global__ __launch_bounds__(256, 2) void conv_tail_kernel(CTArgs a) {
  __shared__ int nbrT[64 * 27];
  __shared__ unsigned short Bs[27 * 8 * 24];
  conv_phase<16, 8>(nbrT, Bs, a.f, a.nbr, a.wt, a.yraw, a.st9, a.n0, a.ntiles);
  __threadfence();
  cg::this_grid().sync();
  __threadfence();
  float* swl = (float*)nbrT;
  float* sbn = swl + 64;
  tail_phase(swl, sbn, a.c0f, a.st9, a.g9, a.b9, a.inv_n, a.lin_w, a.yraw,
             a.out0, a.x0, a.n0);
}

// ---- standalone fallbacks (regular launches) ----
template<int CO>
__global__ __launch_bounds__(256) void bn_kernel(
    const unsigned short* __restrict__ y, const float* __restrict__ stats,
    const float* __restrict__ g, const float* __restrict__ b,
    const unsigned short* __restrict__ skip, unsigned short* __restrict__ out,
    int nout, float inv_n) {
  __shared__ float sA[CO], sC[CO];
  bn_phase<CO>(sA, sC, y, stats, g, b, skip, out, nout, inv_n);
}

__global__ __launch_bounds__(256) void tail_kernel(
    const unsigned short* __restrict__ c0f, const float* __restrict__ st9,
    const float* __restrict__ g9, const float* __restrict__ b9, float inv_n,
    const float* __restrict__ lin_w, const unsigned short* __restrict__ y9,
    float* __restrict__ out0, float* __restrict__ x0, int n0) {
  __shared__ float swl[64];
  __shared__ float sbn[16];
  tail_phase(swl, sbn, c0f, st9, g9, b9, inv_n, lin_w, y9, out0, x0, n0);
}

extern "C" void kernel_launch(void* const* d_in, const int* in_sizes, int n_in,
                              void* d_out, int out_size, void* d_ws, size_t ws_size,
                              hipStream_t stream) {
  const float* feats   = (const float*)d_in[0];
  const int* nbr0      = (const int*)d_in[1];
  const int* nbr_d01   = (const int*)d_in[2];
  const int* nbr1      = (const int*)d_in[3];
  const int* nbr_d12   = (const int*)d_in[4];
  const int* nbr2      = (const int*)d_in[5];
  const int* nbr_d23   = (const int*)d_in[6];
  const int* nbr3      = (const int*)d_in[7];
  const int* nbr_u32   = (const int*)d_in[8];
  const int* nbr_u21   = (const int*)d_in[9];
  const int* nbr_u10   = (const int*)d_in[10];
  const float* w[10];
  const float* g[10];
  const float* b[10];
  for (int i = 0; i < 10; ++i) {
    w[i] = (const float*)d_in[11 + 3 * i];
    g[i] = (const float*)d_in[12 + 3 * i];
    b[i] = (const float*)d_in[13 + 3 * i];
  }
  const float* lin_w = (const float*)d_in[41];

  const int N0 = in_sizes[0] / 16;
  const int N1 = in_sizes[2] / 27;
  const int N2 = in_sizes[4] / 27;
  const int N3 = in_sizes[6] / 27;
  const float i0 = 1.f / N0, i1 = 1.f / N1, i2 = 1.f / N2, i3 = 1.f / N3;

  static const int CIv[10] = {16, 8, 16, 16, 32, 32, 64, 64, 32, 16};
  static const int COv[10] = {8, 16, 16, 32, 32, 64, 64, 32, 16, 8};

  // ---- workspace: fp32 stats region, then bf16 (ushort) region ----
  float* stats = (float*)d_ws;                       // 10 x NBUCKET x 128 floats
  unsigned short* u = (unsigned short*)(stats + 10 * NBUCKET * 128);

  unsigned short* yraw = u; u += (size_t)N1 * 32;    // bf16 y scratch

  unsigned short* wt[10];
  int wcum[11];
  wcum[0] = 0;
  for (int i = 0; i < 10; ++i) {
    wt[i] = u;
    int sz = 27 * CIv[i] * COv[i];
    u += sz;
    wcum[i + 1] = wcum[i] + sz;
  }
  unsigned short* featsb = u; u += (size_t)N0 * 16;
  unsigned short* c0f = u;    u += (size_t)N0 * 8;
  unsigned short* t1  = u;    u += (size_t)N1 * 16;
  unsigned short* c2f = u;    u += (size_t)N1 * 16;
  unsigned short* t2  = u;    u += (size_t)N2 * 32;
  unsigned short* c4f = u;    u += (size_t)N2 * 32;
  unsigned short* t3  = u;    u += (size_t)N3 * 64;
  unsigned short* t4  = u;    u += (size_t)N3 * 64;
  unsigned short* t5  = t2;   // reuse
  unsigned short* t6  = t1;   // reuse
  float* out0 = (float*)d_out;
  float* x0   = (float*)d_out + (size_t)N0 * 8;

  float* s[10];
  for (int i = 0; i < 10; ++i) s[i] = stats + i * NBUCKET * 128;

  // ---- prep (regular launch) ----
  PrepArgs pa;
  for (int i = 0; i < 10; ++i) {
    pa.w[i] = w[i]; pa.wt[i] = wt[i];
    pa.ci[i] = CIv[i]; pa.co[i] = COv[i];
    pa.wcum[i] = wcum[i];
  }
  pa.wcum[10] = wcum[10];
  pa.feats = feats; pa.featsb = featsb;
  pa.nfeat4 = N0 * 16 / 4;
  pa.stats = stats;
  long prep_total = (10 * NBUCKET * 128 / 4) + pa.nfeat4 + wcum[10];
  prep_kernel<<<imin((int)((prep_total + 255) / 256), 2048), 256, 0, stream>>>(pa, prep_total);

  auto bgrid = [](long nout, int co) {
    return imin((int)((nout * co / 4 + 255) / 256), 1024);
  };

  static int s_ncu = 0;
  if (s_ncu == 0) {
    int dev = 0;
    hipGetDevice(&dev);
    hipDeviceProp_t prop{};
    hipGetDeviceProperties(&prop, dev);
    s_ncu = prop.multiProcessorCount > 0 ? prop.multiProcessorCount : 256;
  }

  int tb0 = cdiv(N0, 64), tb1 = cdiv(N1, 64), tb2 = cdiv(N2, 64), tb3 = cdiv(N3, 64);

// one merged cooperative launch per layer; fallback = standalone conv + bn
#define LAYER_CB(CI_, CO_, F_, NBR_, WT_, STATS_, G_, B_, SKIP_, OUT_, NOUT_, NTILES_, INV_) \
  do {                                                                                       \
    CBArgs a_{F_, NBR_, WT_, yraw, STATS_, G_, B_, SKIP_, OUT_, NOUT_, NTILES_, INV_};       \
    static int s_per = 0;                                                                    \
    if (s_per == 0) {                                                                        \
      int p_ = 0;                                                                            \
      if (hipOccupancyMaxActiveBlocksPerMultiprocessor(&p_, conv_bn_kernel<CI_, CO_>,        \
                                                       256, 0) != hipSuccess || p_ < 1)     \
        p_ = 1;                                                                              \
      s_per = p_;                                                                            \
    }                                                                                        \
    int need_ = imax(NTILES_, cdiv((NOUT_) * (CO_) / 4, 256));                               \
    int grid_ = imin(need_, s_per * s_ncu);                                                  \
    if (grid_ < 1) grid_ = 1;                                                                \
    void* ka_[] = {(void*)&a_};                                                              \
    if (hipLaunchCooperativeKernel(conv_bn_kernel<CI_, CO_>, dim3(grid_), dim3(256), ka_,    \
                                   0, stream) != hipSuccess) {                               \
      (void)hipGetLastError();                                                               \
      conv_only_kernel<CI_, CO_><<<imin(NTILES_, 2048), 256, 0, stream>>>(a_);               \
      bn_kernel<CO_><<<bgrid(NOUT_, CO_), 256, 0, stream>>>(                                 \
          yraw, STATS_, G_, B_, SKIP_, OUT_, NOUT_, INV_);                                   \
    }                                                                                        \
  } while (0)

  LAYER_CB(16, 8,  featsb, nbr0,    wt[0], s[0], g[0], b[0], (const unsigned short*)nullptr, c0f, N0, tb0, i0);
  LAYER_CB(8,  16, c0f,    nbr_d01, wt[1], s[1], g[1], b[1], (const unsigned short*)nullptr, t1,  N1, tb1, i1);
  LAYER_CB(16, 16, t1,     nbr1,    wt[2], s[2], g[2], b[2], (const unsigned short*)nullptr, c2f, N1, tb1, i1);
  LAYER_CB(16, 32, c2f,    nbr_d12, wt[3], s[3], g[3], b[3], (const unsigned short*)nullptr, t2,  N2, tb2, i2);
  LAYER_CB(32, 32, t2,     nbr2,    wt[4], s[4], g[4], b[4], (const unsigned short*)nullptr, c4f, N2, tb2, i2);
  LAYER_CB(32, 64, c4f,    nbr_d23, wt[5], s[5], g[5], b[5], (const unsigned short*)nullptr, t3,  N3, tb3, i3);
  LAYER_CB(64, 64, t3,     nbr3,    wt[6], s[6], g[6], b[6], (const unsigned short*)nullptr, t4,  N3, tb3, i3);
  LAYER_CB(64, 32, t4,     nbr_u32, wt[7], s[7], g[7], b[7], c4f,                            t5,  N2, tb2, i2);
  LAYER_CB(32, 16, t5,     nbr_u21, wt[8], s[8], g[8], b[8], c2f,                            t6,  N1, tb1, i1);

#undef LAYER_CB

  // layer 9 + tail merged
  {
    CTArgs a{t6, nbr_u10, wt[9], yraw, s[9], c0f, g[9], b[9], lin_w, out0, x0, N0, tb0, i0};
    static int s_per9 = 0;
    if (s_per9 == 0) {
      int p_ = 0;
      if (hipOccupancyMaxActiveBlocksPerMultiprocessor(&p_, conv_tail_kernel, 256, 0) !=
              hipSuccess || p_ < 1)
        p_ = 1;
      s_per9 = p_;
    }
    int need = imax(tb0, cdiv(N0, 256));
    int grid = imin(need, s_per9 * s_ncu);
    if (grid < 1) grid = 1;
    void* ka[] = {(void*)&a};
    if (hipLaunchCooperativeKernel(conv_tail_kernel, dim3(grid), dim3(256), ka, 0, stream) !=
        hipSuccess) {
      (void)hipGetLastError();
      CBArgs cb{t6, nbr_u10, wt[9], yraw, s[9], nullptr, nullptr, nullptr, nullptr, N0, tb0, 0.f};
      conv_only_kernel<16, 8><<<imin(tb0, 2048), 256, 0, stream>>>(cb);
      tail_kernel<<<imin(cdiv(N0, 256), 1024), 256, 0, stream>>>(
          c0f, s[9], g[9], b[9], i0, lin_w, yraw, out0, x0, N0);
    }
  }
}

// Round 11
// 427.263 us; speedup vs baseline: 4.3431x; 4.3431x over previous
//
#include <hip/hip_runtime.h>

#define EPSV 1e-5f
#define NBUCKET 64

typedef __attribute__((ext_vector_type(8))) short short8;
typedef __attribute__((ext_vector_type(4))) float float4v;

__host__ __device__ static inline int cdiv(int a, int b) { return (a + b - 1) / b; }
__host__ __device__ static inline int imin(int a, int b) { return a < b ? a : b; }

__device__ inline unsigned short f2bf(float x) {
  unsigned u = __float_as_uint(x);
  return (unsigned short)((u + 0x7FFFu + ((u >> 16) & 1u)) >> 16);
}
__device__ inline float bf2f(unsigned short u) {
  return __uint_as_float(((unsigned)u) << 16);
}

struct PrepArgs {
  const float* w[10];
  unsigned short* wt[10];
  int ci[10];
  int co[10];
  int wcum[11];
  const float* feats;
  unsigned short* featsb;
  int nfeat4;
  float* stats;
};

// grid-stride: zero stats + feats fp32->bf16 + weights fp32->bf16 transposed [27][CO][CI]
__global__ __launch_bounds__(256) void prep_kernel(PrepArgs p, long total) {
  const int nstat4 = 10 * NBUCKET * 128 / 4;
  for (long tid0 = (long)blockIdx.x * 256 + threadIdx.x; tid0 < total;
       tid0 += (long)gridDim.x * 256) {
    long tid = tid0;
    if (tid < nstat4) {
      ((float4*)p.stats)[tid] = make_float4(0.f, 0.f, 0.f, 0.f);
      continue;
    }
    tid -= nstat4;
    if (tid < p.nfeat4) {
      float4 v = ((const float4*)p.feats)[tid];
      ushort4 r;
      r.x = f2bf(v.x); r.y = f2bf(v.y); r.z = f2bf(v.z); r.w = f2bf(v.w);
      ((ushort4*)p.featsb)[tid] = r;
      continue;
    }
    tid -= p.nfeat4;
    if (tid >= p.wcum[10]) continue;
    int i = 0;
    while (tid >= p.wcum[i + 1]) ++i;
    int e = (int)(tid - p.wcum[i]);
    int ci = p.ci[i], co = p.co[i];
    int k = e / (ci * co);
    int r = e - k * (ci * co);
    int o = r / ci;
    int c = r - o * ci;
    p.wt[i][((long)k * co + o) * ci + c] = f2bf(p.w[i][((long)k * ci + c) * co + o]);
  }
}

// ================= MFMA gather-GEMM conv (best-known R6 structure) =================
// CI<=16: TWO 64-row tiles per block; all 2*NCHUNK gathers issued before any MFMA
// (sched_barrier(0) pins the phase split). CI==32: one tile, fully-resident A[27].
// CI==64: one tile, 9-group double-buffer. MINW=2 (cap 256 VGPR).
template<int CI, int CO, int MINW>
__global__ __launch_bounds__(256, MINW) void conv_mfma(
    const unsigned short* __restrict__ f, const int* __restrict__ nbr,
    const unsigned short* __restrict__ wt, unsigned short* __restrict__ y,
    float* __restrict__ stats, int nout) {
  constexpr int NCHUNK = (CI == 8) ? 7 : (CI == 16) ? 14 : (CI == 32) ? 27 : 54;
  constexpr int CIP = (CI == 64) ? 64 : (CI == 32) ? 40 : (CI == 16) ? 24 : 12;
  constexpr int RB = (CO < 16) ? CO : 16;  // B rows stored (CO=8 -> 8)
  constexpr bool TWO = (CI <= 16);
  constexpr int NT = TWO ? 2 : 1;

  __shared__ int nbrT[NT * 64 * 27];
  __shared__ unsigned short Bs[27 * RB * CIP];

  const int tid = threadIdx.x;
  const int lane = tid & 63;
  const int wid = tid >> 6;
  const int m = lane & 15;
  const int mm = m & (RB - 1);  // clamped B row for dead lanes (RB power of 2)
  const int quad = lane >> 4;
  const int cbase = blockIdx.y * 16;
  const int co = cbase + m;
  const bool cok = co < CO;

  auto tapof = [&](int c) -> int {
    if constexpr (CI == 8) return c * 4 + quad;
    else if constexpr (CI == 16) return c * 2 + (quad >> 1);
    else if constexpr (CI == 32) return c;
    else return c >> 1;
  };
  auto cioof = [&](int c) -> int {
    if constexpr (CI == 8) return 0;
    else if constexpr (CI == 16) return (quad & 1) * 8;
    else if constexpr (CI == 32) return quad * 8;
    else return ((c & 1) << 5) + quad * 8;
  };
  // LDS B address (short index) for [tap][row][cio]
  auto baddr = [&](int tap, int r, int cio) -> int {
    if constexpr (CI == 64) {
      int byt = (tap * 16 + r) * 128 + cio * 2;
      byt ^= (r & 7) << 4;  // XOR-swizzle 16B slot within the 128B row
      return byt >> 1;
    } else {
      return (tap * RB + r) * CIP + cio;
    }
  };

  const int rowb0 = blockIdx.x * (NT * 64);

  // ---- cooperative weight-slice load into LDS ----
  {
    constexpr int NC8 = CI / 8;
    for (int t = tid; t < 27 * RB * NC8; t += 256) {
      int tap = t / (RB * NC8);
      int r = t - tap * (RB * NC8);
      int mo = r / NC8;
      int c8 = (r - mo * NC8) * 8;
      short8 v;
#pragma unroll
      for (int q = 0; q < 8; ++q) v[q] = 0;
      int c = cbase + mo;
      if (c < CO) v = *(const short8*)(wt + ((long)tap * CO + c) * CI + c8);
      *(short8*)&Bs[baddr(tap, mo, c8)] = v;
    }
  }
  // ---- cooperative nbr stage: contiguous int4 loads (NT tiles) ----
  {
    const long base = (long)rowb0 * 27;
    const long lim = (long)nout * 27;
    for (int j = tid; j < NT * 432; j += 256) {
      long g = base + j * 4;
      int4 v;
      if (g + 4 <= lim) {
        v = *(const int4*)(nbr + g);
      } else {
        v.x = (g + 0 < lim) ? nbr[g + 0] : -1;
        v.y = (g + 1 < lim) ? nbr[g + 1] : -1;
        v.z = (g + 2 < lim) ? nbr[g + 2] : -1;
        v.w = (g + 3 < lim) ? nbr[g + 3] : -1;
      }
      *(int4*)&nbrT[j * 4] = v;
    }
  }
  __syncthreads();

  const int rowb = rowb0 + wid * 16;
  const int lrow = (wid * 16 + m) * 27;
  float sum = 0.f, sq = 0.f;

  if constexpr (TWO) {
    int idx0[NCHUNK], idx1[NCHUNK];
#pragma unroll
    for (int c = 0; c < NCHUNK; ++c) {
      int tap = tapof(c);
      idx0[c] = (tap < 27) ? nbrT[lrow + tap] : -1;
      idx1[c] = (tap < 27) ? nbrT[1728 + lrow + tap] : -1;
    }
    short8 A0[NCHUNK], A1[NCHUNK];
#pragma unroll
    for (int c = 0; c < NCHUNK; ++c) {
      short8 a;
#pragma unroll
      for (int q = 0; q < 8; ++q) a[q] = 0;
      if (idx0[c] >= 0) a = *(const short8*)(f + (long)idx0[c] * CI + cioof(c));
      A0[c] = a;
    }
#pragma unroll
    for (int c = 0; c < NCHUNK; ++c) {
      short8 a;
#pragma unroll
      for (int q = 0; q < 8; ++q) a[q] = 0;
      if (idx1[c] >= 0) a = *(const short8*)(f + (long)idx1[c] * CI + cioof(c));
      A1[c] = a;
    }
    __builtin_amdgcn_sched_barrier(0);  // all gathers issued before MFMA phase
    float4v acc0 = {0.f, 0.f, 0.f, 0.f};
    float4v acc1 = {0.f, 0.f, 0.f, 0.f};
#pragma unroll
    for (int c = 0; c < NCHUNK; ++c) {
      int tap = tapof(c);
      int tapc = tap < 27 ? tap : 26;  // A=0 masks the clamped B
      short8 bf = *(const short8*)&Bs[baddr(tapc, mm, cioof(c))];
      acc0 = __builtin_amdgcn_mfma_f32_16x16x32_bf16(A0[c], bf, acc0, 0, 0, 0);
      acc1 = __builtin_amdgcn_mfma_f32_16x16x32_bf16(A1[c], bf, acc1, 0, 0, 0);
    }
#pragma unroll
    for (int r = 0; r < 4; ++r) {
      float v0 = acc0[r];
      int o0 = rowb + quad * 4 + r;
      if (cok && o0 < nout) y[(long)o0 * CO + co] = f2bf(v0);
      sum += v0;
      sq = fmaf(v0, v0, sq);
      float v1 = acc1[r];
      int o1 = rowb + 64 + quad * 4 + r;
      if (cok && o1 < nout) y[(long)o1 * CO + co] = f2bf(v1);
      sum += v1;
      sq = fmaf(v1, v1, sq);
    }
  } else if constexpr (CI == 32) {
    int idxs[27];
#pragma unroll
    for (int t = 0; t < 27; ++t) idxs[t] = nbrT[lrow + t];
    short8 A[27];
#pragma unroll
    for (int c = 0; c < 27; ++c) {
      short8 a;
#pragma unroll
      for (int q = 0; q < 8; ++q) a[q] = 0;
      if (idxs[c] >= 0) a = *(const short8*)(f + (long)idxs[c] * 32 + quad * 8);
      A[c] = a;
    }
    __builtin_amdgcn_sched_barrier(0);
    float4v acc = {0.f, 0.f, 0.f, 0.f};
#pragma unroll
    for (int c = 0; c < 27; ++c) {
      short8 bf = *(const short8*)&Bs[baddr(c, mm, quad * 8)];
      acc = __builtin_amdgcn_mfma_f32_16x16x32_bf16(A[c], bf, acc, 0, 0, 0);
    }
#pragma unroll
    for (int r = 0; r < 4; ++r) {
      float v = acc[r];
      int orow = rowb + quad * 4 + r;
      if (cok && orow < nout) y[(long)orow * CO + co] = f2bf(v);
      sum += v;
      sq = fmaf(v, v, sq);
    }
  } else {  // CI == 64
    constexpr int G = 9;
    constexpr int NG = NCHUNK / G;
    short8 A[2][G];
    auto load_group = [&](int g, int bi) {
#pragma unroll
      for (int j = 0; j < G; ++j) {
        const int c = g * G + j;
        const int tap = tapof(c);
        int idx = nbrT[lrow + tap];
        short8 a;
#pragma unroll
        for (int q = 0; q < 8; ++q) a[q] = 0;
        if (idx >= 0) a = *(const short8*)(f + (long)idx * CI + cioof(c));
        A[bi][j] = a;
      }
    };
    float4v acc = {0.f, 0.f, 0.f, 0.f};
    load_group(0, 0);
#pragma unroll
    for (int g = 0; g < NG; ++g) {
      const int cur = g & 1;
      if (g + 1 < NG) load_group(g + 1, cur ^ 1);
#pragma unroll
      for (int j = 0; j < G; ++j) {
        const int c = g * G + j;
        short8 bf = *(const short8*)&Bs[baddr(tapof(c), mm, cioof(c))];
        acc = __builtin_amdgcn_mfma_f32_16x16x32_bf16(A[cur][j], bf, acc, 0, 0, 0);
      }
    }
#pragma unroll
    for (int r = 0; r < 4; ++r) {
      float v = acc[r];
      int orow = rowb + quad * 4 + r;
      if (cok && orow < nout) y[(long)orow * CO + co] = f2bf(v);
      sum += v;
      sq = fmaf(v, v, sq);
    }
  }

  // one atomic pair per wave
  sum += __shfl_xor(sum, 16); sq += __shfl_xor(sq, 16);
  sum += __shfl_xor(sum, 32); sq += __shfl_xor(sq, 32);
  if (quad == 0 && cok) {
    float* st = stats + ((((unsigned)blockIdx.x * 4 + wid) & (NBUCKET - 1)) << 7);
    atomicAdd(&st[co], sum);
    atomicAdd(&st[64 + co], sq);
  }
}

// ---- BN+ReLU (+bf16 skip), bf16 y -> bf16 feature map, grid-stride ----
template<int CO>
__global__ __launch_bounds__(256) void bn_relu_bf16(
    const unsigned short* __restrict__ y, const float* __restrict__ stats,
    const float* __restrict__ g, const float* __restrict__ b,
    const unsigned short* __restrict__ skip, unsigned short* __restrict__ out,
    int nout, float inv_n) {
  __shared__ float sA[CO], sC[CO];
  if ((int)threadIdx.x < CO) {
    int o = threadIdx.x;
    float su = 0.f, sq = 0.f;
#pragma unroll 8
    for (int bk = 0; bk < NBUCKET; ++bk) {
      su += stats[bk * 128 + o];
      sq += stats[bk * 128 + 64 + o];
    }
    float mu = su * inv_n;
    float var = sq * inv_n - mu * mu;
    float a = g[o] * rsqrtf(var + EPSV);
    sA[o] = a;
    sC[o] = fmaf(-mu, a, b[o]);
  }
  __syncthreads();
  long total4 = (long)nout * CO / 4;
  for (long i4 = (long)blockIdx.x * 256 + threadIdx.x; i4 < total4;
       i4 += (long)gridDim.x * 256) {
    int o = (int)((i4 * 4) % CO);
    ushort4 v = ((const ushort4*)y)[i4];
    float vv[4] = {bf2f(v.x), bf2f(v.y), bf2f(v.z), bf2f(v.w)};
    unsigned short rr[4];
#pragma unroll
    for (int j = 0; j < 4; ++j) {
      float x = fmaxf(fmaf(vv[j], sA[o + j], sC[o + j]), 0.f);
      if (skip) x += bf2f(skip[i4 * 4 + j]);
      rr[j] = f2bf(x);
    }
    ushort4 r;
    r.x = rr[0]; r.y = rr[1]; r.z = rr[2]; r.w = rr[3];
    ((ushort4*)out)[i4] = r;
  }
}

// ---- fused tail: x0 = c0f + relu(bn(y9)); out0 = x0 @ lin_w.T, grid-stride ----
__global__ __launch_bounds__(256) void tail_kernel(
    const unsigned short* __restrict__ c0f, const float* __restrict__ st9,
    const float* __restrict__ g9, const float* __restrict__ b9, float inv_n,
    const float* __restrict__ lin_w, const unsigned short* __restrict__ y9,
    float* __restrict__ out0, float* __restrict__ x0, int n0) {
  __shared__ float swl[64];
  __shared__ float sbn[16];
  if (threadIdx.x < 64) swl[threadIdx.x] = lin_w[threadIdx.x];
  if (threadIdx.x < 8) {
    int o = threadIdx.x;
    float su = 0.f, sq = 0.f;
#pragma unroll 8
    for (int bk = 0; bk < NBUCKET; ++bk) {
      su += st9[bk * 128 + o];
      sq += st9[bk * 128 + 64 + o];
    }
    float mu = su * inv_n;
    float var = sq * inv_n - mu * mu;
    float a = g9[o] * rsqrtf(var + EPSV);
    sbn[o] = a;
    sbn[8 + o] = fmaf(-mu, a, b9[o]);
  }
  __syncthreads();
  for (int n = blockIdx.x * 256 + (int)threadIdx.x; n < n0; n += gridDim.x * 256) {
    const ushort4* pr = (const ushort4*)(y9 + (long)n * 8);
    ushort4 r0 = pr[0], r1 = pr[1];
    unsigned short rw[8] = {r0.x, r0.y, r0.z, r0.w, r1.x, r1.y, r1.z, r1.w};
    const ushort4* pc = (const ushort4*)(c0f + (long)n * 8);
    ushort4 c0 = pc[0], c1 = pc[1];
    unsigned short cs[8] = {c0.x, c0.y, c0.z, c0.w, c1.x, c1.y, c1.z, c1.w};
    float xv[8];
#pragma unroll
    for (int c = 0; c < 8; ++c)
      xv[c] = bf2f(cs[c]) + fmaxf(fmaf(bf2f(rw[c]), sbn[c], sbn[8 + c]), 0.f);
    *(float4*)(x0 + (long)n * 8) = make_float4(xv[0], xv[1], xv[2], xv[3]);
    *(float4*)(x0 + (long)n * 8 + 4) = make_float4(xv[4], xv[5], xv[6], xv[7]);
    float ov[8];
#pragma unroll
    for (int j = 0; j < 8; ++j) {
      float s = 0.f;
#pragma unroll
      for (int c = 0; c < 8; ++c) s = fmaf(xv[c], swl[j * 8 + c], s);
      ov[j] = s;
    }
    *(float4*)(out0 + (long)n * 8) = make_float4(ov[0], ov[1], ov[2], ov[3]);
    *(float4*)(out0 + (long)n * 8 + 4) = make_float4(ov[4], ov[5], ov[6], ov[7]);
  }
}

extern "C" void kernel_launch(void* const* d_in, const int* in_sizes, int n_in,
                              void* d_out, int out_size, void* d_ws, size_t ws_size,
                              hipStream_t stream) {
  const float* feats   = (const float*)d_in[0];
  const int* nbr0      = (const int*)d_in[1];
  const int* nbr_d01   = (const int*)d_in[2];
  const int* nbr1      = (const int*)d_in[3];
  const int* nbr_d12   = (const int*)d_in[4];
  const int* nbr2      = (const int*)d_in[5];
  const int* nbr_d23   = (const int*)d_in[6];
  const int* nbr3      = (const int*)d_in[7];
  const int* nbr_u32   = (const int*)d_in[8];
  const int* nbr_u21   = (const int*)d_in[9];
  const int* nbr_u10   = (const int*)d_in[10];
  const float* w[10];
  const float* g[10];
  const float* b[10];
  for (int i = 0; i < 10; ++i) {
    w[i] = (const float*)d_in[11 + 3 * i];
    g[i] = (const float*)d_in[12 + 3 * i];
    b[i] = (const float*)d_in[13 + 3 * i];
  }
  const float* lin_w = (const float*)d_in[41];

  const int N0 = in_sizes[0] / 16;
  const int N1 = in_sizes[2] / 27;
  const int N2 = in_sizes[4] / 27;
  const int N3 = in_sizes[6] / 27;
  const float i0 = 1.f / N0, i1 = 1.f / N1, i2 = 1.f / N2, i3 = 1.f / N3;

  static const int CIv[10] = {16, 8, 16, 16, 32, 32, 64, 64, 32, 16};
  static const int COv[10] = {8, 16, 16, 32, 32, 64, 64, 32, 16, 8};

  // ---- workspace: fp32 stats region, then bf16 (ushort) region ----
  float* stats = (float*)d_ws;                       // 10 x NBUCKET x 128 floats
  unsigned short* u = (unsigned short*)(stats + 10 * NBUCKET * 128);

  unsigned short* yraw = u; u += (size_t)N1 * 32;    // bf16 y scratch

  unsigned short* wt[10];
  int wcum[11];
  wcum[0] = 0;
  for (int i = 0; i < 10; ++i) {
    wt[i] = u;
    int sz = 27 * CIv[i] * COv[i];
    u += sz;
    wcum[i + 1] = wcum[i] + sz;
  }
  unsigned short* featsb = u; u += (size_t)N0 * 16;
  unsigned short* c0f = u;    u += (size_t)N0 * 8;
  unsigned short* t1  = u;    u += (size_t)N1 * 16;
  unsigned short* c2f = u;    u += (size_t)N1 * 16;
  unsigned short* t2  = u;    u += (size_t)N2 * 32;
  unsigned short* c4f = u;    u += (size_t)N2 * 32;
  unsigned short* t3  = u;    u += (size_t)N3 * 64;
  unsigned short* t4  = u;    u += (size_t)N3 * 64;
  unsigned short* t5  = t2;   // reuse
  unsigned short* t6  = t1;   // reuse
  float* out0 = (float*)d_out;
  float* x0   = (float*)d_out + (size_t)N0 * 8;

  float* s[10];
  for (int i = 0; i < 10; ++i) s[i] = stats + i * NBUCKET * 128;

  // ---- prep (grid-stride) ----
  PrepArgs pa;
  for (int i = 0; i < 10; ++i) {
    pa.w[i] = w[i]; pa.wt[i] = wt[i];
    pa.ci[i] = CIv[i]; pa.co[i] = COv[i];
    pa.wcum[i] = wcum[i];
  }
  pa.wcum[10] = wcum[10];
  pa.feats = feats; pa.featsb = featsb;
  pa.nfeat4 = N0 * 16 / 4;
  pa.stats = stats;
  long prep_total = (10 * NBUCKET * 128 / 4) + pa.nfeat4 + wcum[10];
  prep_kernel<<<imin((int)((prep_total + 255) / 256), 2048), 256, 0, stream>>>(pa, prep_total);

  auto bgrid = [](long nout, int co) {
    return imin((int)((nout * co / 4 + 255) / 256), 1024);
  };

  // grids: 128 rows/block for CI<=16 (two tiles), 64 rows/block otherwise
  int g2_0 = cdiv(N0, 128), g2_1 = cdiv(N1, 128), g2_2 = cdiv(N2, 128);
  int g1_1 = cdiv(N1, 64), g1_2 = cdiv(N2, 64), g1_3 = cdiv(N3, 64);

  // conv0: 16->8 @ N0
  conv_mfma<16, 8, 2><<<dim3(g2_0, 1), 256, 0, stream>>>(featsb, nbr0, wt[0], yraw, s[0], N0);
  bn_relu_bf16<8><<<bgrid(N0, 8), 256, 0, stream>>>(yraw, s[0], g[0], b[0], nullptr, c0f, N0, i0);

  // conv1: 8->16 down to N1
  conv_mfma<8, 16, 4><<<dim3(g2_1, 1), 256, 0, stream>>>(c0f, nbr_d01, wt[1], yraw, s[1], N1);
  bn_relu_bf16<16><<<bgrid(N1, 16), 256, 0, stream>>>(yraw, s[1], g[1], b[1], nullptr, t1, N1, i1);

  // conv2: 16->16 @ N1
  conv_mfma<16, 16, 2><<<dim3(g2_1, 1), 256, 0, stream>>>(t1, nbr1, wt[2], yraw, s[2], N1);
  bn_relu_bf16<16><<<bgrid(N1, 16), 256, 0, stream>>>(yraw, s[2], g[2], b[2], nullptr, c2f, N1, i1);

  // conv3: 16->32 down to N2
  conv_mfma<16, 32, 2><<<dim3(g2_2, 2), 256, 0, stream>>>(c2f, nbr_d12, wt[3], yraw, s[3], N2);
  bn_relu_bf16<32><<<bgrid(N2, 32), 256, 0, stream>>>(yraw, s[3], g[3], b[3], nullptr, t2, N2, i2);

  // conv4: 32->32 @ N2
  conv_mfma<32, 32, 2><<<dim3(g1_2, 2), 256, 0, stream>>>(t2, nbr2, wt[4], yraw, s[4], N2);
  bn_relu_bf16<32><<<bgrid(N2, 32), 256, 0, stream>>>(yraw, s[4], g[4], b[4], nullptr, c4f, N2, i2);

  // conv5: 32->64 down to N3
  conv_mfma<32, 64, 2><<<dim3(g1_3, 4), 256, 0, stream>>>(c4f, nbr_d23, wt[5], yraw, s[5], N3);
  bn_relu_bf16<64><<<bgrid(N3, 64), 256, 0, stream>>>(yraw, s[5], g[5], b[5], nullptr, t3, N3, i3);

  // conv6: 64->64 @ N3
  conv_mfma<64, 64, 2><<<dim3(g1_3, 4), 256, 0, stream>>>(t3, nbr3, wt[6], yraw, s[6], N3);
  bn_relu_bf16<64><<<bgrid(N3, 64), 256, 0, stream>>>(yraw, s[6], g[6], b[6], nullptr, t4, N3, i3);

  // conv7: 64->32 up to N2; x2 = c4f + relu(bn(y7))
  conv_mfma<64, 32, 2><<<dim3(g1_2, 2), 256, 0, stream>>>(t4, nbr_u32, wt[7], yraw, s[7], N2);
  bn_relu_bf16<32><<<bgrid(N2, 32), 256, 0, stream>>>(yraw, s[7], g[7], b[7], c4f, t5, N2, i2);

  // conv8: 32->16 up to N1; x1 = c2f + relu(bn(y8))
  conv_mfma<32, 16, 2><<<dim3(g1_1, 1), 256, 0, stream>>>(t5, nbr_u21, wt[8], yraw, s[8], N1);
  bn_relu_bf16<16><<<bgrid(N1, 16), 256, 0, stream>>>(yraw, s[8], g[8], b[8], c2f, t6, N1, i1);

  // conv9: 16->8 up to N0; y9 bf16 in yraw
  conv_mfma<16, 8, 2><<<dim3(g2_0, 1), 256, 0, stream>>>(t6, nbr_u10, wt[9], yraw, s[9], N0);

  // tail: x0 = c0f + relu(bn(y9)); out0 = x0 @ lin_w.T
  tail_kernel<<<imin(cdiv(N0, 256), 1024), 256, 0, stream>>>(
      c0f, s[9], g[9], b[9], i0, lin_w, yraw, out0, x0, N0);
}